// Round 5
// baseline (618.367 us; speedup 1.0000x reference)
//
#include <hip/hip_runtime.h>
#include <hip/hip_bf16.h>

#define NNODES 100000
#define NEDGES 3200000
#define DIN 512
#define DOUT 128
#define NPASS 8
#define PCOLS 16          // bf16 columns per panel (panel = 3.2 MB, fits 4 MB XCD L2)
#define BPP 25000         // blocks per pass: 100000 rows / 4 waves per block

typedef __attribute__((ext_vector_type(8))) short bf16x8;   // 8 bf16 = 4 VGPRs
typedef __attribute__((ext_vector_type(4))) float f32x4;
typedef __attribute__((ext_vector_type(4))) unsigned short us4;

static __device__ __forceinline__ unsigned short f2bf(float f) {
  union { float f; unsigned u; } v; v.f = f;
  unsigned r = v.u + 0x7fffu + ((v.u >> 16) & 1u);
  return (unsigned short)(r >> 16);
}
static __device__ __forceinline__ unsigned pkbf(float a, float b) {
  union { __hip_bfloat162 h2; unsigned u; } t;
  t.h2 = __float22bfloat162_rn(make_float2(a, b));   // v_cvt_pk_bf16_f32
  return t.u;
}
static __device__ __forceinline__ float bflo(unsigned g) {
  union { unsigned u; float f; } v; v.u = g << 16; return v.f;
}
static __device__ __forceinline__ float bfhi(unsigned g) {
  union { unsigned u; float f; } v; v.u = g & 0xffff0000u; return v.f;
}

// ---- W transpose + cast: Wt[n][k] bf16 from W[k][n] fp32 ----
__global__ void wt_kernel(const float* __restrict__ W, unsigned short* __restrict__ Wt) {
  int idx = blockIdx.x * blockDim.x + threadIdx.x;   // 65536 threads
  int n = idx >> 9, k = idx & 511;
  Wt[n * DIN + k] = f2bf(W[k * DOUT + n]);
}

// ---- row_ptr[r] = lower_bound(adj_rows, r) ----
__global__ void rowptr_kernel(const int* __restrict__ rows, int* __restrict__ rp) {
  int r = blockIdx.x * blockDim.x + threadIdx.x;
  if (r > NNODES) return;
  int lo = 0, hi = NEDGES;
  while (lo < hi) { int mid = (lo + hi) >> 1; if (rows[mid] < r) lo = mid + 1; else hi = mid; }
  rp[r] = lo;
}

// ---- pack (col 17b | val 15b fixed-point) into one dword per edge ----
__global__ void pack_kernel(const int* __restrict__ cols, const float* __restrict__ vals,
                            unsigned* __restrict__ pk) {
  int i = blockIdx.x * blockDim.x + threadIdx.x;
  if (i >= NEDGES) return;
  unsigned q = (unsigned)(vals[i] * 32768.0f);
  if (q > 32767u) q = 32767u;
  pk[i] = (q << 17) | (unsigned)cols[i];
}

// ---- GEMM: h (panel-major bf16 [NPASS][NNODES][16]) = x @ W ----
#define BM 128
#define BK 64
#define LDA 72   // padded K stride (elems), 144 B row pitch keeps 16B alignment

__launch_bounds__(256, 3)
__global__ void gemm_kernel(const float* __restrict__ x, const unsigned short* __restrict__ Wt,
                            unsigned short* __restrict__ h) {
  __shared__ unsigned short Asb[BM][LDA];
  __shared__ unsigned short Bsb[DOUT][LDA];
  const int t = threadIdx.x;
  const int lane = t & 63;
  const int w = t >> 6;
  const int wm = w >> 1, wn = w & 1;
  const int m0 = blockIdx.x * BM;

  f32x4 acc[4][4] = {};

  const int rr = t >> 4;           // 0..15
  const int c4 = (t & 15) * 4;     // 0..60

  for (int kt = 0; kt < DIN; kt += BK) {
    #pragma unroll
    for (int it = 0; it < 8; ++it) {
      int row = it * 16 + rr;
      int gm = m0 + row;
      float4 v = make_float4(0.f, 0.f, 0.f, 0.f);
      if (gm < NNODES) v = *(const float4*)(x + (long)gm * DIN + kt + c4);
      uint2 bb; bb.x = pkbf(v.x, v.y); bb.y = pkbf(v.z, v.w);
      *(uint2*)&Asb[row][c4] = bb;
    }
    #pragma unroll
    for (int it = 0; it < 8; ++it) {
      int n = it * 16 + rr;
      us4 b = *(const us4*)(Wt + n * DIN + kt + c4);
      *(us4*)&Bsb[n][c4] = b;
    }
    __syncthreads();

    #pragma unroll
    for (int ks = 0; ks < 2; ++ks) {
      const int ko = ks * 32 + (lane >> 4) * 8;
      bf16x8 af[4], bfr[4];
      #pragma unroll
      for (int fm = 0; fm < 4; ++fm)
        af[fm] = *(const bf16x8*)&Asb[wm * 64 + fm * 16 + (lane & 15)][ko];
      #pragma unroll
      for (int fn = 0; fn < 4; ++fn)
        bfr[fn] = *(const bf16x8*)&Bsb[wn * 64 + fn * 16 + (lane & 15)][ko];
      #pragma unroll
      for (int fm = 0; fm < 4; ++fm)
        #pragma unroll
        for (int fn = 0; fn < 4; ++fn)
          acc[fm][fn] = __builtin_amdgcn_mfma_f32_16x16x32_bf16(af[fm], bfr[fn], acc[fm][fn], 0, 0, 0);
    }
    __syncthreads();
  }

  // epilogue: D lane mapping col = lane&15, row = (lane>>4)*4 + i (m89-verified).
  // global col = wn*64 + fn*16 + col_in -> panel pi = wn*4+fn, within-panel col_in.
  const int col_in = lane & 15;
  const int rbase = (lane >> 4) * 4;
  #pragma unroll
  for (int fm = 0; fm < 4; ++fm) {
    #pragma unroll
    for (int i = 0; i < 4; ++i) {
      int gm = m0 + wm * 64 + fm * 16 + rbase + i;
      if (gm < NNODES) {
        #pragma unroll
        for (int fn = 0; fn < 4; ++fn) {
          int pi = wn * 4 + fn;
          h[(size_t)pi * (NNODES * PCOLS) + (size_t)gm * PCOLS + col_in] = f2bf(acc[fm][fn][i]);
        }
      }
    }
  }
}

// ---- SpMM + relu, 8 column-panel passes; wave = (row, pass) ----
// lane: g = lane>>3 (edge slot), d = lane&7 (dword within 32B panel row)
__global__ void spmm8_kernel(const unsigned short* __restrict__ hp, const unsigned* __restrict__ pk,
                             const int* __restrict__ rp, float* __restrict__ out) {
  int bid = blockIdx.x;
  int p = bid / BPP;
  int b = bid - p * BPP;
  int wave = threadIdx.x >> 6;
  int lane = threadIdx.x & 63;
  int row = b * 4 + wave;
  int g = lane >> 3, d = lane & 7;
  int s = __builtin_amdgcn_readfirstlane(rp[row]);
  int e = __builtin_amdgcn_readfirstlane(rp[row + 1]);
  const unsigned* panel = (const unsigned*)hp + (size_t)p * (NNODES * 8);
  float ax = 0.f, ay = 0.f;
  int i = s + g;
  for (; i + 8 < e; i += 16) {
    unsigned e0 = pk[i], e1 = pk[i + 8];
    unsigned c0 = e0 & 0x1FFFFu, c1 = e1 & 0x1FFFFu;
    float v0 = (float)(e0 >> 17) * (1.f / 32768.f);
    float v1 = (float)(e1 >> 17) * (1.f / 32768.f);
    unsigned g0 = panel[c0 * 8 + d];
    unsigned g1 = panel[c1 * 8 + d];
    ax += v0 * bflo(g0); ay += v0 * bfhi(g0);
    ax += v1 * bflo(g1); ay += v1 * bfhi(g1);
  }
  if (i < e) {
    unsigned e0 = pk[i];
    unsigned c0 = e0 & 0x1FFFFu;
    float v0 = (float)(e0 >> 17) * (1.f / 32768.f);
    unsigned g0 = panel[c0 * 8 + d];
    ax += v0 * bflo(g0); ay += v0 * bfhi(g0);
  }
  // reduce across the 8 edge-slot groups (stride-8 butterfly keeps d fixed)
  ax += __shfl_xor(ax, 8);  ay += __shfl_xor(ay, 8);
  ax += __shfl_xor(ax, 16); ay += __shfl_xor(ay, 16);
  ax += __shfl_xor(ax, 32); ay += __shfl_xor(ay, 32);
  if (g == 0) {
    float2 o; o.x = ax > 0.f ? ax : 0.f; o.y = ay > 0.f ? ay : 0.f;
    *(float2*)(out + (size_t)row * DOUT + p * PCOLS + d * 2) = o;
  }
}

extern "C" void kernel_launch(void* const* d_in, const int* in_sizes, int n_in,
                              void* d_out, int out_size, void* d_ws, size_t ws_size,
                              hipStream_t stream) {
  const float* x        = (const float*)d_in[0];
  const float* W        = (const float*)d_in[1];
  const int*   adj_rows = (const int*)d_in[2];
  const int*   adj_cols = (const int*)d_in[3];
  const float* adj_vals = (const float*)d_in[4];
  float* out = (float*)d_out;

  char* ws = (char*)d_ws;
  unsigned short* hp = (unsigned short*)ws;                          // 25,600,000 B
  unsigned short* Wt = (unsigned short*)(ws + 25600000);             // 131,072 B
  int* rp            = (int*)(ws + 25600000 + 131072);               // 400,004 B
  unsigned* pk       = (unsigned*)(ws + 25600000 + 131072 + 400004); // 12,800,000 B

  wt_kernel<<<256, 256, 0, stream>>>(W, Wt);
  rowptr_kernel<<<(NNODES + 1 + 255) / 256, 256, 0, stream>>>(adj_rows, rp);
  pack_kernel<<<(NEDGES + 255) / 256, 256, 0, stream>>>(adj_cols, adj_vals, pk);
  gemm_kernel<<<(NNODES + BM - 1) / BM, 256, 0, stream>>>(x, Wt, hp);
  spmm8_kernel<<<NPASS * BPP, 256, 0, stream>>>(hp, pk, rp, out);
}